// Round 1
// baseline (1047.555 us; speedup 1.0000x reference)
//
#include <hip/hip_runtime.h>
#include <math.h>

// Fused MHA-like layer, fp32 decomposition:
//   Q/K/V = relu(x@W + b); E = QK^T/32 (causal, -10000 mask == exact 0 after
//   fp32 softmax underflow); P = softmax(E); Y = P@V; out = relu(Y@Wo + bo).
// Workspace layout (floats): Q[4M] K[4M] V[4M] P[8M]; Y reuses Q (Q dead after QK^T).

#define TM 128
#define TN 128
#define TK 16

// C[M,N] = (relu?)(A[M,K] @ B[K,N] (+ bias)), optional causal k-bound (for P@V).
template<bool RELU, bool HAS_BIAS, bool CAUSAL_K>
__global__ __launch_bounds__(256)
void gemm_nn(const float* __restrict__ A, const float* __restrict__ B,
             const float* __restrict__ bias, float* __restrict__ C,
             int M, int N, int K,
             long long sA, long long sB, long long sC)
{
  A += (long long)blockIdx.z * sA;
  B += (long long)blockIdx.z * sB;
  C += (long long)blockIdx.z * sC;
  const int m0 = blockIdx.y * TM;
  const int n0 = blockIdx.x * TN;
  const int kend = CAUSAL_K ? ((m0 + TM < K) ? (m0 + TM) : K) : K;

  __shared__ float As[TK][TM];
  __shared__ float Bs[TK][TN];

  const int tid = threadIdx.x;
  const int tx = tid & 15;
  const int ty = tid >> 4;

  float acc[8][8];
  #pragma unroll
  for (int i = 0; i < 8; ++i)
    #pragma unroll
    for (int j = 0; j < 8; ++j) acc[i][j] = 0.f;

  for (int k0 = 0; k0 < kend; k0 += TK) {
    // A tile: 128 rows x 16 cols, transposed into As[k][m]
    #pragma unroll
    for (int t = 0; t < 2; ++t) {
      int idx = tid + t * 256;           // 0..511
      int row = idx >> 2;                // 0..127
      int c4  = (idx & 3) << 2;          // 0,4,8,12
      float4 a = *(const float4*)(A + (size_t)(m0 + row) * K + (k0 + c4));
      As[c4 + 0][row] = a.x; As[c4 + 1][row] = a.y;
      As[c4 + 2][row] = a.z; As[c4 + 3][row] = a.w;
    }
    // B tile: 16 rows x 128 cols, direct
    #pragma unroll
    for (int t = 0; t < 2; ++t) {
      int idx = tid + t * 256;           // 0..511
      int kr = idx >> 5;                 // 0..15
      int c4 = (idx & 31) << 2;          // 0..124
      *(float4*)(&Bs[kr][c4]) = *(const float4*)(B + (size_t)(k0 + kr) * N + (n0 + c4));
    }
    __syncthreads();
    #pragma unroll
    for (int kk = 0; kk < TK; ++kk) {
      float4 a0 = *(const float4*)(&As[kk][ty * 4]);
      float4 a1 = *(const float4*)(&As[kk][ty * 4 + 64]);
      float4 b0 = *(const float4*)(&Bs[kk][tx * 4]);
      float4 b1 = *(const float4*)(&Bs[kk][tx * 4 + 64]);
      float av[8] = {a0.x, a0.y, a0.z, a0.w, a1.x, a1.y, a1.z, a1.w};
      float bv[8] = {b0.x, b0.y, b0.z, b0.w, b1.x, b1.y, b1.z, b1.w};
      #pragma unroll
      for (int i = 0; i < 8; ++i)
        #pragma unroll
        for (int j = 0; j < 8; ++j)
          acc[i][j] = fmaf(av[i], bv[j], acc[i][j]);
    }
    __syncthreads();
  }

  float bvals[8];
  if (HAS_BIAS) {
    #pragma unroll
    for (int jj = 0; jj < 8; ++jj) {
      int n = n0 + ((jj < 4) ? (tx * 4 + jj) : (64 + tx * 4 + jj - 4));
      bvals[jj] = bias[n];
    }
  }
  #pragma unroll
  for (int ii = 0; ii < 8; ++ii) {
    int m = m0 + ((ii < 4) ? (ty * 4 + ii) : (64 + ty * 4 + ii - 4));
    float* crow = C + (size_t)m * N + n0;
    float o[8];
    #pragma unroll
    for (int jj = 0; jj < 8; ++jj) {
      float v = acc[ii][jj];
      if (HAS_BIAS) v += bvals[jj];
      if (RELU) v = fmaxf(v, 0.f);
      o[jj] = v;
    }
    *(float4*)(crow + tx * 4)      = make_float4(o[0], o[1], o[2], o[3]);
    *(float4*)(crow + 64 + tx * 4) = make_float4(o[4], o[5], o[6], o[7]);
  }
}

// E[i,j] = scale * sum_d Q[i,d] * K[j,d]; tiles entirely above the causal
// diagonal are skipped (softmax never reads j > i).
__global__ __launch_bounds__(256)
void gemm_qkt(const float* __restrict__ Q, const float* __restrict__ Km,
              float* __restrict__ E, int S, int D, float scale)
{
  const int i0 = blockIdx.y * TM;
  const int j0 = blockIdx.x * TN;
  if (j0 > i0 + (TM - 1)) return;   // fully masked tile

  const float* Qb = Q + (size_t)blockIdx.z * S * D;
  const float* Kb = Km + (size_t)blockIdx.z * S * D;
  float* Eb = E + (size_t)blockIdx.z * S * S;

  __shared__ float As[TK][TM];
  __shared__ float Bs[TK][TN];

  const int tid = threadIdx.x;
  const int tx = tid & 15;
  const int ty = tid >> 4;

  float acc[8][8];
  #pragma unroll
  for (int i = 0; i < 8; ++i)
    #pragma unroll
    for (int j = 0; j < 8; ++j) acc[i][j] = 0.f;

  for (int k0 = 0; k0 < D; k0 += TK) {
    #pragma unroll
    for (int t = 0; t < 2; ++t) {
      int idx = tid + t * 256;
      int row = idx >> 2;
      int c4  = (idx & 3) << 2;
      float4 a = *(const float4*)(Qb + (size_t)(i0 + row) * D + (k0 + c4));
      As[c4 + 0][row] = a.x; As[c4 + 1][row] = a.y;
      As[c4 + 2][row] = a.z; As[c4 + 3][row] = a.w;
    }
    #pragma unroll
    for (int t = 0; t < 2; ++t) {
      int idx = tid + t * 256;
      int row = idx >> 2;                // key index 0..127
      int c4  = (idx & 3) << 2;
      float4 kv = *(const float4*)(Kb + (size_t)(j0 + row) * D + (k0 + c4));
      Bs[c4 + 0][row] = kv.x; Bs[c4 + 1][row] = kv.y;
      Bs[c4 + 2][row] = kv.z; Bs[c4 + 3][row] = kv.w;
    }
    __syncthreads();
    #pragma unroll
    for (int kk = 0; kk < TK; ++kk) {
      float4 a0 = *(const float4*)(&As[kk][ty * 4]);
      float4 a1 = *(const float4*)(&As[kk][ty * 4 + 64]);
      float4 b0 = *(const float4*)(&Bs[kk][tx * 4]);
      float4 b1 = *(const float4*)(&Bs[kk][tx * 4 + 64]);
      float av[8] = {a0.x, a0.y, a0.z, a0.w, a1.x, a1.y, a1.z, a1.w};
      float bv[8] = {b0.x, b0.y, b0.z, b0.w, b1.x, b1.y, b1.z, b1.w};
      #pragma unroll
      for (int i = 0; i < 8; ++i)
        #pragma unroll
        for (int j = 0; j < 8; ++j)
          acc[i][j] = fmaf(av[i], bv[j], acc[i][j]);
    }
    __syncthreads();
  }

  #pragma unroll
  for (int ii = 0; ii < 8; ++ii) {
    int m = i0 + ((ii < 4) ? (ty * 4 + ii) : (64 + ty * 4 + ii - 4));
    float* erow = Eb + (size_t)m * S + j0;
    float o[8];
    #pragma unroll
    for (int jj = 0; jj < 8; ++jj) o[jj] = acc[ii][jj] * scale;
    *(float4*)(erow + tx * 4)      = make_float4(o[0], o[1], o[2], o[3]);
    *(float4*)(erow + 64 + tx * 4) = make_float4(o[4], o[5], o[6], o[7]);
  }
}

// In-place causal softmax over row i: reads j in [0,i], writes full row
// (zeros for j > i so P@V can be a plain GEMM). One 256-thr block per row.
__global__ __launch_bounds__(256)
void softmax_causal(float* __restrict__ E, int S)
{
  const int i = blockIdx.x;
  float* row = E + ((size_t)blockIdx.y * S + i) * S;
  const int tid = threadIdx.x;
  const int n = i + 1;

  float vals[8];
  float m = -3.0e38f;
  #pragma unroll
  for (int t = 0; t < 8; ++t) {
    int j = tid + t * 256;
    float v = (j < n) ? row[j] : -3.0e38f;
    vals[t] = v;
    m = fmaxf(m, v);
  }
  #pragma unroll
  for (int o = 32; o > 0; o >>= 1) m = fmaxf(m, __shfl_down(m, o, 64));

  __shared__ float rmax[4];
  __shared__ float rsum[4];
  const int wave = tid >> 6;
  if ((tid & 63) == 0) rmax[wave] = m;
  __syncthreads();
  m = fmaxf(fmaxf(rmax[0], rmax[1]), fmaxf(rmax[2], rmax[3]));

  float s = 0.f;
  #pragma unroll
  for (int t = 0; t < 8; ++t) {
    int j = tid + t * 256;
    float e = (j < n) ? expf(vals[t] - m) : 0.f;
    vals[t] = e;
    s += e;
  }
  #pragma unroll
  for (int o = 32; o > 0; o >>= 1) s += __shfl_down(s, o, 64);
  if ((tid & 63) == 0) rsum[wave] = s;
  __syncthreads();
  s = rsum[0] + rsum[1] + rsum[2] + rsum[3];

  const float inv = 1.0f / s;
  #pragma unroll
  for (int t = 0; t < 8; ++t) {
    int j = tid + t * 256;
    if (j < S) row[j] = vals[t] * inv;
  }
}

extern "C" void kernel_launch(void* const* d_in, const int* in_sizes, int n_in,
                              void* d_out, int out_size, void* d_ws, size_t ws_size,
                              hipStream_t stream) {
  const float* x  = (const float*)d_in[0];
  const float* Wq = (const float*)d_in[1];
  const float* bq = (const float*)d_in[2];
  const float* Wk = (const float*)d_in[3];
  const float* bk = (const float*)d_in[4];
  const float* Wv = (const float*)d_in[5];
  const float* bv = (const float*)d_in[6];
  const float* Wo = (const float*)d_in[7];
  const float* bo = (const float*)d_in[8];
  float* out = (float*)d_out;

  const int Bn = 2, S = 2048, D = 1024;
  const int M = Bn * S;                    // 4096

  float* ws = (float*)d_ws;
  float* Q  = ws;                          // M*D floats
  float* Kt = ws + (size_t)M * D;          // M*D
  float* V  = ws + 2 * (size_t)M * D;      // M*D
  float* P  = ws + 3 * (size_t)M * D;      // Bn*S*S
  float* Y  = Q;                           // Q is dead after QK^T

  dim3 blk(256);
  dim3 gProj(D / TN, M / TM);              // (8, 32)

  gemm_nn<true, true, false><<<gProj, blk, 0, stream>>>(x, Wq, bq, Q, M, D, D, 0, 0, 0);
  gemm_nn<true, true, false><<<gProj, blk, 0, stream>>>(x, Wk, bk, Kt, M, D, D, 0, 0, 0);
  gemm_nn<true, true, false><<<gProj, blk, 0, stream>>>(x, Wv, bv, V, M, D, D, 0, 0, 0);

  dim3 gS(S / TN, S / TM, Bn);             // (16, 16, 2)
  gemm_qkt<<<gS, blk, 0, stream>>>(Q, Kt, P, S, D, 0.03125f);

  softmax_causal<<<dim3(S, Bn), blk, 0, stream>>>(P, S);

  dim3 gPV(D / TN, S / TM, Bn);            // (8, 16, 2)
  gemm_nn<false, false, true><<<gPV, blk, 0, stream>>>(
      P, V, nullptr, Y, S, D, S,
      (long long)S * S, (long long)S * D, (long long)S * D);

  gemm_nn<true, true, false><<<gProj, blk, 0, stream>>>(Y, Wo, bo, out, M, D, D, 0, 0, 0);
}

// Round 2
// 306.328 us; speedup vs baseline: 3.4197x; 3.4197x over previous
//
#include <hip/hip_runtime.h>
#include <math.h>

// fp16-MFMA decomposition of the fused MHA-like layer (fp32 accumulate):
//   xh = f16(x); WT = f16(W^T) for q,k,v,o
//   Q/K/V = relu(xh@W + b)            [f16, M x D]
//   VT = V^T per batch                [f16, D x S]
//   E = (Q K^T)/32                    [f16, causal tile-skip]
//   P = softmax_causal(E) in-place    [fp32 math, f16 IO; zeros for j>i]
//   Y = P @ V (k-loop capped at diagonal tile)
//   out = relu(Y@Wo + bo)             [fp32 out]
// GEMM structure = m97 ladder: 128x128 tile, 4 waves, 4x4 frags of
// mfma_f32_16x16x32_f16, BK=32, global_load_lds width=16, B^T operands.

typedef _Float16 f16x8 __attribute__((ext_vector_type(8)));
typedef float f32x4 __attribute__((ext_vector_type(4)));

#define TM 128
#define TN 128
#define BK 32

__device__ __forceinline__ void gload_lds16(const void* g, void* l) {
  __builtin_amdgcn_global_load_lds(
      (const __attribute__((address_space(1))) void*)g,
      (__attribute__((address_space(3))) void*)l, 16, 0, 0);
}

// C = act(A @ B (+bias)); A [M,K] f16 row-major, BT [N,K] f16 row-major (B^T).
// CAUSAL: 0 = none, 1 = QK^T (skip tiles with n0 > m0, apply scale),
//         2 = PV (k-loop capped at m0+TM).
template<bool RELU, bool HAS_BIAS, int CAUSAL, typename OT>
__global__ __launch_bounds__(256) void gemm_f16(
    const _Float16* __restrict__ A, const _Float16* __restrict__ BT,
    const float* __restrict__ bias, OT* __restrict__ C,
    int M, int N, int K, float scale,
    long long sA, long long sB, long long sC)
{
  const int m0 = blockIdx.y * TM;
  const int n0 = blockIdx.x * TN;
  if (CAUSAL == 1 && n0 > m0) return;   // fully masked score tile
  A  += (long long)blockIdx.z * sA;
  BT += (long long)blockIdx.z * sB;
  C  += (long long)blockIdx.z * sC;
  const int kend = (CAUSAL == 2) ? ((m0 + TM < K) ? m0 + TM : K) : K;

  __shared__ _Float16 Ah[TM * BK];   // [row][k], 64 B rows, no pad (global_load_lds)
  __shared__ _Float16 Bh[TN * BK];

  const int tid  = threadIdx.x;
  const int lane = tid & 63;
  const int wid  = tid >> 6;
  const int wm   = (wid >> 1) * 64;   // wave's 64x64 sub-tile
  const int wn   = (wid & 1) * 64;
  const int l15  = lane & 15;
  const int quad = lane >> 4;

  f32x4 acc[4][4];
  #pragma unroll
  for (int i = 0; i < 4; ++i)
    #pragma unroll
    for (int j = 0; j < 4; ++j)
      acc[i][j] = (f32x4){0.f, 0.f, 0.f, 0.f};

  // staging: each wave fills 32 rows of each tile via 2 global_load_lds each;
  // lane i of an instr covers row base+i/4, k-bytes (i%4)*16 (contiguous LDS).
  const int r0 = wid * 32 + (lane >> 2);   // + t*16 per instr
  const int kq = (lane & 3) * 8;           // halves

  for (int k0 = 0; k0 < kend; k0 += BK) {
    const _Float16* Ag = A  + (long long)(m0 + r0) * K + k0 + kq;
    const _Float16* Bg = BT + (long long)(n0 + r0) * K + k0 + kq;
    gload_lds16(Ag,           Ah + (wid * 32)      * BK);
    gload_lds16(Ag + 16LL * K, Ah + (wid * 32 + 16) * BK);
    gload_lds16(Bg,           Bh + (wid * 32)      * BK);
    gload_lds16(Bg + 16LL * K, Bh + (wid * 32 + 16) * BK);
    __syncthreads();

    const f16x8* ap = (const f16x8*)(Ah + (wm + l15) * BK + quad * 8);
    const f16x8* bp = (const f16x8*)(Bh + (wn + l15) * BK + quad * 8);
    f16x8 af[4], bf[4];
    #pragma unroll
    for (int t = 0; t < 4; ++t) {
      af[t] = ap[t * 64];   // t*16 rows * 32 halves / 8
      bf[t] = bp[t * 64];
    }
    #pragma unroll
    for (int mt = 0; mt < 4; ++mt)
      #pragma unroll
      for (int nt = 0; nt < 4; ++nt)
        acc[mt][nt] = __builtin_amdgcn_mfma_f32_16x16x32_f16(
            af[mt], bf[nt], acc[mt][nt], 0, 0, 0);
    __syncthreads();
  }

  // epilogue: C/D layout col = lane&15, row = quad*4 + reg (HW-verified)
  float bvals[4];
  if (HAS_BIAS) {
    #pragma unroll
    for (int nt = 0; nt < 4; ++nt)
      bvals[nt] = bias[n0 + wn + nt * 16 + l15];
  }
  #pragma unroll
  for (int mt = 0; mt < 4; ++mt) {
    #pragma unroll
    for (int nt = 0; nt < 4; ++nt) {
      const int col = n0 + wn + nt * 16 + l15;
      #pragma unroll
      for (int r = 0; r < 4; ++r) {
        const int row = m0 + wm + mt * 16 + quad * 4 + r;
        float v = acc[mt][nt][r] * scale;
        if (HAS_BIAS) v += bvals[nt];
        if (RELU) v = fmaxf(v, 0.f);
        C[(long long)row * N + col] = (OT)v;
      }
    }
  }
}

// fp32 -> fp16 elementwise, 8 per thread
__global__ __launch_bounds__(256) void cvt_f32_f16(
    const float* __restrict__ in, _Float16* __restrict__ out)
{
  const long long i = ((long long)blockIdx.x * 256 + threadIdx.x) * 8;
  float4 a = *(const float4*)(in + i);
  float4 b = *(const float4*)(in + i + 4);
  f16x8 o = {(_Float16)a.x, (_Float16)a.y, (_Float16)a.z, (_Float16)a.w,
             (_Float16)b.x, (_Float16)b.y, (_Float16)b.z, (_Float16)b.w};
  *(f16x8*)(out + i) = o;
}

// W [K,N] fp32 -> WT [N,K] fp16 (64x64 tiles via padded LDS)
__global__ __launch_bounds__(256) void cvtT_f32_f16(
    const float* __restrict__ W, _Float16* __restrict__ WT, int K, int N)
{
  __shared__ _Float16 t[64][72];
  const int k0 = blockIdx.x * 64, n0 = blockIdx.y * 64;
  const int tid = threadIdx.x;
  #pragma unroll
  for (int it = 0; it < 4; ++it) {
    int idx = tid + it * 256;
    int r = idx >> 4, c4 = (idx & 15) << 2;
    float4 w = *(const float4*)(W + (long long)(k0 + r) * N + n0 + c4);
    t[r][c4 + 0] = (_Float16)w.x; t[r][c4 + 1] = (_Float16)w.y;
    t[r][c4 + 2] = (_Float16)w.z; t[r][c4 + 3] = (_Float16)w.w;
  }
  __syncthreads();
  #pragma unroll
  for (int it = 0; it < 2; ++it) {
    int idx = tid + it * 256;
    int r = idx >> 3, c8 = (idx & 7) << 3;
    f16x8 o;
    #pragma unroll
    for (int j = 0; j < 8; ++j) o[j] = t[c8 + j][r];
    *(f16x8*)(WT + (long long)(n0 + r) * K + k0 + c8) = o;
  }
}

// V [S,D] f16 -> VT [D,S] f16, per batch z
__global__ __launch_bounds__(256) void transp_f16(
    const _Float16* __restrict__ V, _Float16* __restrict__ VT, int S, int D)
{
  __shared__ _Float16 t[64][72];
  const _Float16* Vb = V + (long long)blockIdx.z * S * D;
  _Float16* VTb = VT + (long long)blockIdx.z * D * S;
  const int s0 = blockIdx.x * 64, d0 = blockIdx.y * 64;
  const int tid = threadIdx.x;
  #pragma unroll
  for (int it = 0; it < 2; ++it) {
    int idx = tid + it * 256;
    int r = idx >> 3, c8 = (idx & 7) << 3;
    f16x8 v = *(const f16x8*)(Vb + (long long)(s0 + r) * D + d0 + c8);
    *(f16x8*)&t[r][c8] = v;
  }
  __syncthreads();
  #pragma unroll
  for (int it = 0; it < 2; ++it) {
    int idx = tid + it * 256;
    int r = idx >> 3, c8 = (idx & 7) << 3;
    f16x8 o;
    #pragma unroll
    for (int j = 0; j < 8; ++j) o[j] = t[c8 + j][r];
    *(f16x8*)(VTb + (long long)(d0 + r) * S + s0 + c8) = o;
  }
}

// in-place causal softmax, fp32 math, f16 IO; writes zeros for j > i
__global__ __launch_bounds__(256) void softmax_causal_h(
    _Float16* __restrict__ E, int S)
{
  const int i = blockIdx.x;
  _Float16* row = E + ((long long)blockIdx.y * S + i) * S;
  const int tid = threadIdx.x;
  const int n = i + 1;
  const int j0 = tid * 8;

  f16x8 hv = *(const f16x8*)(row + j0);
  float vals[8];
  float m = -3.0e38f;
  #pragma unroll
  for (int t = 0; t < 8; ++t) {
    float v = (j0 + t < n) ? (float)hv[t] : -3.0e38f;
    vals[t] = v;
    m = fmaxf(m, v);
  }
  #pragma unroll
  for (int o = 32; o > 0; o >>= 1) m = fmaxf(m, __shfl_down(m, o, 64));

  __shared__ float rmax[4];
  __shared__ float rsum[4];
  const int wave = tid >> 6;
  if ((tid & 63) == 0) rmax[wave] = m;
  __syncthreads();
  m = fmaxf(fmaxf(rmax[0], rmax[1]), fmaxf(rmax[2], rmax[3]));

  float s = 0.f;
  #pragma unroll
  for (int t = 0; t < 8; ++t) {
    float e = (j0 + t < n) ? expf(vals[t] - m) : 0.f;
    vals[t] = e;
    s += e;
  }
  #pragma unroll
  for (int o = 32; o > 0; o >>= 1) s += __shfl_down(s, o, 64);
  if ((tid & 63) == 0) rsum[wave] = s;
  __syncthreads();
  s = rsum[0] + rsum[1] + rsum[2] + rsum[3];

  const float inv = 1.0f / s;
  f16x8 ov;
  #pragma unroll
  for (int t = 0; t < 8; ++t) ov[t] = (_Float16)(vals[t] * inv);
  *(f16x8*)(row + j0) = ov;
}

extern "C" void kernel_launch(void* const* d_in, const int* in_sizes, int n_in,
                              void* d_out, int out_size, void* d_ws, size_t ws_size,
                              hipStream_t stream) {
  const float* x  = (const float*)d_in[0];
  const float* Wq = (const float*)d_in[1];
  const float* bq = (const float*)d_in[2];
  const float* Wk = (const float*)d_in[3];
  const float* bk = (const float*)d_in[4];
  const float* Wv = (const float*)d_in[5];
  const float* bv = (const float*)d_in[6];
  const float* Wo = (const float*)d_in[7];
  const float* bo = (const float*)d_in[8];
  float* out = (float*)d_out;

  const int Bn = 2, S = 2048, D = 1024;
  const int M = Bn * S;                       // 4096
  const size_t MD = (size_t)M * D;            // 4M elems
  const size_t DD = (size_t)D * D;            // 1M
  const size_t SS = (size_t)Bn * S * S;       // 8M

  _Float16* ws  = (_Float16*)d_ws;
  _Float16* xh  = ws;                 // MD
  _Float16* WqT = xh + MD;            // DD
  _Float16* WkT = WqT + DD;
  _Float16* WvT = WkT + DD;
  _Float16* WoT = WvT + DD;
  _Float16* Qh  = WoT + DD;           // MD
  _Float16* Kh  = Qh + MD;            // MD
  _Float16* Vh  = Kh + MD;            // MD
  _Float16* VTh = Vh + MD;            // MD
  _Float16* E   = VTh + MD;           // SS
  _Float16* Yh  = E + SS;             // MD   (total 36M halves = 72 MB)

  dim3 blk(256);

  // converts
  cvt_f32_f16<<<dim3((unsigned)(MD / (256 * 8))), blk, 0, stream>>>(x, xh);
  dim3 gW(D / 64, D / 64);
  cvtT_f32_f16<<<gW, blk, 0, stream>>>(Wq, WqT, D, D);
  cvtT_f32_f16<<<gW, blk, 0, stream>>>(Wk, WkT, D, D);
  cvtT_f32_f16<<<gW, blk, 0, stream>>>(Wv, WvT, D, D);
  cvtT_f32_f16<<<gW, blk, 0, stream>>>(Wo, WoT, D, D);

  // projections: relu(x@W + b) -> f16
  dim3 gProj(D / TN, M / TM);                  // (8, 32)
  gemm_f16<true, true, 0, _Float16><<<gProj, blk, 0, stream>>>(
      xh, WqT, bq, Qh, M, D, D, 1.0f, 0, 0, 0);
  gemm_f16<true, true, 0, _Float16><<<gProj, blk, 0, stream>>>(
      xh, WkT, bk, Kh, M, D, D, 1.0f, 0, 0, 0);
  gemm_f16<true, true, 0, _Float16><<<gProj, blk, 0, stream>>>(
      xh, WvT, bv, Vh, M, D, D, 1.0f, 0, 0, 0);

  // V transpose for PV's B^T operand
  transp_f16<<<dim3(S / 64, D / 64, Bn), blk, 0, stream>>>(Vh, VTh, S, D);

  // E = QK^T / 32 (causal tile skip)
  dim3 gS(S / TN, S / TM, Bn);                 // (16, 16, 2)
  gemm_f16<false, false, 1, _Float16><<<gS, blk, 0, stream>>>(
      Qh, Kh, nullptr, E, S, S, D, 0.03125f,
      (long long)S * D, (long long)S * D, (long long)S * S);

  softmax_causal_h<<<dim3(S, Bn), blk, 0, stream>>>(E, S);

  // Y = P @ V (k capped at diagonal)
  dim3 gPV(D / TN, S / TM, Bn);                // (8, 16, 2)
  gemm_f16<false, false, 2, _Float16><<<gPV, blk, 0, stream>>>(
      E, VTh, nullptr, Yh, S, D, S, 1.0f,
      (long long)S * S, (long long)D * S, (long long)S * D);

  // out = relu(Y@Wo + bo) -> fp32
  gemm_f16<true, true, 0, float><<<gProj, blk, 0, stream>>>(
      Yh, WoT, bo, out, M, D, D, 1.0f, 0, 0, 0);
}

// Round 3
// 235.110 us; speedup vs baseline: 4.4556x; 1.3029x over previous
//
#include <hip/hip_runtime.h>
#include <math.h>

// fp16-MFMA fused MHA-like layer (fp32 accumulate), round 3:
//  - single fused QKV GEMM (N=3072 vs concat W^T) -> 768 blocks = 3/CU
//  - packed lower-triangular grid for QK^T (TN=64, no dead blocks)
//  - PV with TM=64 (512 blocks), out-proj with TN=64 (512 blocks)
//  - one weight-convert kernel (z=4) ; 8 dispatches total

typedef _Float16 f16x8 __attribute__((ext_vector_type(8)));
typedef float f32x4 __attribute__((ext_vector_type(4)));

#define BK 32

__device__ __forceinline__ void gload_lds16(const void* g, void* l) {
  __builtin_amdgcn_global_load_lds(
      (const __attribute__((address_space(1))) void*)g,
      (__attribute__((address_space(3))) void*)l, 16, 0, 0);
}

// Generic MFMA GEMM: C = act(A @ B (+bias)), A [M,K] f16 rm, BT [N,K] f16 rm.
// 256 threads, waves 2x2 over (TMp, TNp). CAUSAL: 0 none, 1 QK^T (packed
// triangular grid in blockIdx.x, scale), 2 PV (kend = m0+TMp).
// MULTI: demux C/bias by n0 (QKV fusion), per-matrix row stride Nout.
template<bool RELU, bool HAS_BIAS, int CAUSAL, int TMp, int TNp, bool MULTI, typename OT>
__global__ __launch_bounds__(256) void gemm_f16(
    const _Float16* __restrict__ A, const _Float16* __restrict__ BT,
    const float* __restrict__ bias0, const float* __restrict__ bias1,
    const float* __restrict__ bias2,
    OT* __restrict__ C0, OT* __restrict__ C1, OT* __restrict__ C2,
    int M, int Nout, int K, float scale,
    long long sA, long long sB, long long sC)
{
  int m0, n0;
  if (CAUSAL == 1) {
    int bx = blockIdx.x;                       // packed lower-tri, 2(i+1) j-tiles per i
    int i = (int)((sqrtf(4.f * bx + 1.f) - 1.f) * 0.5f);
    while ((i + 1) * (i + 2) <= bx) ++i;
    while (i * (i + 1) > bx) --i;
    int j = bx - i * (i + 1);
    m0 = i * TMp;
    n0 = j * TNp;
  } else {
    m0 = blockIdx.y * TMp;
    n0 = blockIdx.x * TNp;
  }
  A  += (long long)blockIdx.z * sA;
  BT += (long long)blockIdx.z * sB;
  const int kend = (CAUSAL == 2) ? ((m0 + TMp < K) ? m0 + TMp : K) : K;

  __shared__ _Float16 Ah[TMp * BK];
  __shared__ _Float16 Bh[TNp * BK];

  const int tid  = threadIdx.x;
  const int lane = tid & 63;
  const int wid  = tid >> 6;
  const int wm   = (wid >> 1) * (TMp / 2);
  const int wn   = (wid & 1) * (TNp / 2);
  const int l15  = lane & 15;
  const int quad = lane >> 4;
  constexpr int MT = TMp / 32;
  constexpr int NT = TNp / 32;

  f32x4 acc[MT][NT];
  #pragma unroll
  for (int i = 0; i < MT; ++i)
    #pragma unroll
    for (int j = 0; j < NT; ++j)
      acc[i][j] = (f32x4){0.f, 0.f, 0.f, 0.f};

  constexpr int AI = TMp / 64;   // global_load_lds instrs per wave (A)
  constexpr int BI = TNp / 64;
  const int ar = wid * (TMp / 4);
  const int br = wid * (TNp / 4);
  const int rl = lane >> 2;
  const int kq = (lane & 3) * 8;

  for (int k0 = 0; k0 < kend; k0 += BK) {
    #pragma unroll
    for (int t = 0; t < AI; ++t)
      gload_lds16(A + (long long)(m0 + ar + t * 16 + rl) * K + k0 + kq,
                  Ah + (ar + t * 16) * BK);
    #pragma unroll
    for (int t = 0; t < BI; ++t)
      gload_lds16(BT + (long long)(n0 + br + t * 16 + rl) * K + k0 + kq,
                  Bh + (br + t * 16) * BK);
    __syncthreads();

    const f16x8* ap = (const f16x8*)(Ah + (wm + l15) * BK + quad * 8);
    const f16x8* bp = (const f16x8*)(Bh + (wn + l15) * BK + quad * 8);
    f16x8 af[MT], bf[NT];
    #pragma unroll
    for (int t = 0; t < MT; ++t) af[t] = ap[t * 64];
    #pragma unroll
    for (int t = 0; t < NT; ++t) bf[t] = bp[t * 64];
    #pragma unroll
    for (int mt = 0; mt < MT; ++mt)
      #pragma unroll
      for (int nt = 0; nt < NT; ++nt)
        acc[mt][nt] = __builtin_amdgcn_mfma_f32_16x16x32_f16(
            af[mt], bf[nt], acc[mt][nt], 0, 0, 0);
    __syncthreads();
  }

  // epilogue; C/D layout: col = lane&15, row = quad*4 + reg (HW-verified)
  const int mat = MULTI ? (n0 / Nout) : 0;
  const float* bias = HAS_BIAS ? (mat == 0 ? bias0 : (mat == 1 ? bias1 : bias2)) : nullptr;
  OT* C = (mat == 0 ? C0 : (mat == 1 ? C1 : C2)) + (long long)blockIdx.z * sC;
  const int c0 = MULTI ? (n0 - mat * Nout) : n0;

  float bvals[NT];
  if (HAS_BIAS) {
    #pragma unroll
    for (int nt = 0; nt < NT; ++nt)
      bvals[nt] = bias[c0 + wn + nt * 16 + l15];
  }
  #pragma unroll
  for (int mt = 0; mt < MT; ++mt) {
    #pragma unroll
    for (int nt = 0; nt < NT; ++nt) {
      const int col = c0 + wn + nt * 16 + l15;
      #pragma unroll
      for (int r = 0; r < 4; ++r) {
        const int row = m0 + wm + mt * 16 + quad * 4 + r;
        float v = acc[mt][nt][r] * scale;
        if (HAS_BIAS) v += bvals[nt];
        if (RELU) v = fmaxf(v, 0.f);
        C[(long long)row * Nout + col] = (OT)v;
      }
    }
  }
}

// fp32 -> fp16 elementwise, 8 per thread
__global__ __launch_bounds__(256) void cvt_f32_f16(
    const float* __restrict__ in, _Float16* __restrict__ out)
{
  const long long i = ((long long)blockIdx.x * 256 + threadIdx.x) * 8;
  float4 a = *(const float4*)(in + i);
  float4 b = *(const float4*)(in + i + 4);
  f16x8 o = {(_Float16)a.x, (_Float16)a.y, (_Float16)a.z, (_Float16)a.w,
             (_Float16)b.x, (_Float16)b.y, (_Float16)b.z, (_Float16)b.w};
  *(f16x8*)(out + i) = o;
}

// All four W [K,N] fp32 -> concat WT [4N, K] fp16; z selects matrix.
__global__ __launch_bounds__(256) void cvtT_all(
    const float* __restrict__ W0, const float* __restrict__ W1,
    const float* __restrict__ W2, const float* __restrict__ W3,
    _Float16* __restrict__ WT, int K, int N)
{
  __shared__ _Float16 t[64][72];
  const int z = blockIdx.z;
  const float* W = (z == 0) ? W0 : (z == 1) ? W1 : (z == 2) ? W2 : W3;
  _Float16* dst = WT + (long long)z * K * N;
  const int k0 = blockIdx.x * 64, n0 = blockIdx.y * 64;
  const int tid = threadIdx.x;
  #pragma unroll
  for (int it = 0; it < 4; ++it) {
    int idx = tid + it * 256;
    int r = idx >> 4, c4 = (idx & 15) << 2;
    float4 w = *(const float4*)(W + (long long)(k0 + r) * N + n0 + c4);
    t[r][c4 + 0] = (_Float16)w.x; t[r][c4 + 1] = (_Float16)w.y;
    t[r][c4 + 2] = (_Float16)w.z; t[r][c4 + 3] = (_Float16)w.w;
  }
  __syncthreads();
  #pragma unroll
  for (int it = 0; it < 2; ++it) {
    int idx = tid + it * 256;
    int r = idx >> 3, c8 = (idx & 7) << 3;
    f16x8 o;
    #pragma unroll
    for (int j = 0; j < 8; ++j) o[j] = t[c8 + j][r];
    *(f16x8*)(dst + (long long)(n0 + r) * K + k0 + c8) = o;
  }
}

// V [S,D] f16 -> VT [D,S] f16, per batch z
__global__ __launch_bounds__(256) void transp_f16(
    const _Float16* __restrict__ V, _Float16* __restrict__ VT, int S, int D)
{
  __shared__ _Float16 t[64][72];
  const _Float16* Vb = V + (long long)blockIdx.z * S * D;
  _Float16* VTb = VT + (long long)blockIdx.z * D * S;
  const int s0 = blockIdx.x * 64, d0 = blockIdx.y * 64;
  const int tid = threadIdx.x;
  #pragma unroll
  for (int it = 0; it < 2; ++it) {
    int idx = tid + it * 256;
    int r = idx >> 3, c8 = (idx & 7) << 3;
    f16x8 v = *(const f16x8*)(Vb + (long long)(s0 + r) * D + d0 + c8);
    *(f16x8*)&t[r][c8] = v;
  }
  __syncthreads();
  #pragma unroll
  for (int it = 0; it < 2; ++it) {
    int idx = tid + it * 256;
    int r = idx >> 3, c8 = (idx & 7) << 3;
    f16x8 o;
    #pragma unroll
    for (int j = 0; j < 8; ++j) o[j] = t[c8 + j][r];
    *(f16x8*)(VTb + (long long)(d0 + r) * S + s0 + c8) = o;
  }
}

// in-place causal softmax, fp32 math, f16 IO; zeros for j > i
__global__ __launch_bounds__(256) void softmax_causal_h(
    _Float16* __restrict__ E, int S)
{
  const int i = blockIdx.x;
  _Float16* row = E + ((long long)blockIdx.y * S + i) * S;
  const int tid = threadIdx.x;
  const int n = i + 1;
  const int j0 = tid * 8;

  f16x8 hv = *(const f16x8*)(row + j0);
  float vals[8];
  float m = -3.0e38f;
  #pragma unroll
  for (int t = 0; t < 8; ++t) {
    float v = (j0 + t < n) ? (float)hv[t] : -3.0e38f;
    vals[t] = v;
    m = fmaxf(m, v);
  }
  #pragma unroll
  for (int o = 32; o > 0; o >>= 1) m = fmaxf(m, __shfl_down(m, o, 64));

  __shared__ float rmax[4];
  __shared__ float rsum[4];
  const int wave = tid >> 6;
  if ((tid & 63) == 0) rmax[wave] = m;
  __syncthreads();
  m = fmaxf(fmaxf(rmax[0], rmax[1]), fmaxf(rmax[2], rmax[3]));

  float s = 0.f;
  #pragma unroll
  for (int t = 0; t < 8; ++t) {
    float e = (j0 + t < n) ? expf(vals[t] - m) : 0.f;
    vals[t] = e;
    s += e;
  }
  #pragma unroll
  for (int o = 32; o > 0; o >>= 1) s += __shfl_down(s, o, 64);
  if ((tid & 63) == 0) rsum[wave] = s;
  __syncthreads();
  s = rsum[0] + rsum[1] + rsum[2] + rsum[3];

  const float inv = 1.0f / s;
  f16x8 ov;
  #pragma unroll
  for (int t = 0; t < 8; ++t) ov[t] = (_Float16)(vals[t] * inv);
  *(f16x8*)(row + j0) = ov;
}

extern "C" void kernel_launch(void* const* d_in, const int* in_sizes, int n_in,
                              void* d_out, int out_size, void* d_ws, size_t ws_size,
                              hipStream_t stream) {
  const float* x  = (const float*)d_in[0];
  const float* Wq = (const float*)d_in[1];
  const float* bq = (const float*)d_in[2];
  const float* Wk = (const float*)d_in[3];
  const float* bk = (const float*)d_in[4];
  const float* Wv = (const float*)d_in[5];
  const float* bv = (const float*)d_in[6];
  const float* Wo = (const float*)d_in[7];
  const float* bo = (const float*)d_in[8];
  float* out = (float*)d_out;

  const int Bn = 2, S = 2048, D = 1024;
  const int M = Bn * S;                       // 4096
  const size_t MD = (size_t)M * D;            // 4M elems
  const size_t DD = (size_t)D * D;            // 1M
  const size_t SS = (size_t)Bn * S * S;       // 8M

  _Float16* ws   = (_Float16*)d_ws;
  _Float16* xh   = ws;                 // MD
  _Float16* Wcat = xh + MD;            // 4*DD: Wq^T,Wk^T,Wv^T,Wo^T
  _Float16* Qh   = Wcat + 4 * DD;      // MD
  _Float16* Kh   = Qh + MD;            // MD
  _Float16* Vh   = Kh + MD;            // MD
  _Float16* VTh  = Vh + MD;            // MD
  _Float16* E    = VTh + MD;           // SS
  _Float16* Yh   = E + SS;             // MD

  dim3 blk(256);

  cvt_f32_f16<<<dim3((unsigned)(MD / 2048)), blk, 0, stream>>>(x, xh);
  cvtT_all<<<dim3(D / 64, D / 64, 4), blk, 0, stream>>>(Wq, Wk, Wv, Wo, Wcat, D, D);

  // fused QKV: relu(x@W{q,k,v} + b) -> f16, grid 768 = 3 blocks/CU
  gemm_f16<true, true, 0, 128, 128, true, _Float16>
      <<<dim3(3 * D / 128, M / 128), blk, 0, stream>>>(
      xh, Wcat, bq, bk, bv, Qh, Kh, Vh, M, D, D, 1.0f, 0, 0, 0);

  transp_f16<<<dim3(S / 64, D / 64, Bn), blk, 0, stream>>>(Vh, VTh, S, D);

  // E = QK^T/32, packed triangular grid: 272 tiles/batch (TM=128, TN=64)
  gemm_f16<false, false, 1, 128, 64, false, _Float16>
      <<<dim3(272, 1, Bn), blk, 0, stream>>>(
      Qh, Kh, nullptr, nullptr, nullptr, E, nullptr, nullptr,
      S, S, D, 0.03125f, (long long)S * D, (long long)S * D, (long long)S * S);

  softmax_causal_h<<<dim3(S, Bn), blk, 0, stream>>>(E, S);

  // Y = P @ V, TM=64 -> 512 blocks, k capped at diagonal
  gemm_f16<false, false, 2, 64, 128, false, _Float16>
      <<<dim3(D / 128, S / 64, Bn), blk, 0, stream>>>(
      E, VTh, nullptr, nullptr, nullptr, Yh, nullptr, nullptr,
      S, D, S, 1.0f, (long long)S * S, (long long)D * S, (long long)S * D);

  // out = relu(Y@Wo + bo) -> fp32, TN=64 -> 512 blocks
  gemm_f16<true, true, 0, 128, 64, false, float>
      <<<dim3(D / 64, M / 128), blk, 0, stream>>>(
      Yh, Wcat + 3 * DD, bo, nullptr, nullptr, out, nullptr, nullptr,
      M, D, D, 1.0f, 0, 0, 0);
}

// Round 4
// 209.294 us; speedup vs baseline: 5.0052x; 1.1234x over previous
//
#include <hip/hip_runtime.h>
#include <math.h>

// fp16-MFMA fused MHA-like layer (fp32 accumulate), round 4:
//  - BK=64 K-loop (half the barriers) with XOR-swizzled LDS chunks
//    (conflict-free ds_read_b128 despite 128B row stride)
//  - associativity: out = relu(P @ (V@Wo) + bo) -- kills V-transpose and Y
//  - 7 dispatches: cvt, cvtT, QKV, QK^T, VW, softmax, P@VW->out

typedef _Float16 f16x8 __attribute__((ext_vector_type(8)));
typedef float f32x4 __attribute__((ext_vector_type(4)));

#define BK 64   // k-halves per LDS tile; row stride 128 B

__device__ __forceinline__ void gload_lds16(const void* g, void* l) {
  __builtin_amdgcn_global_load_lds(
      (const __attribute__((address_space(1))) void*)g,
      (__attribute__((address_space(3))) void*)l, 16, 0, 0);
}

// C = act(A @ B (+bias)); A [M,K] f16 rm, BT [N,K] f16 rm.
// CAUSAL: 0 none, 1 QK^T (packed triangular blockIdx.x, scale), 2 kend=m0+TMp.
// MULTI: demux C/bias by n0 (QKV fusion).
// LDS layout: row-major [row][chunk] where chunk = 8 halves (16 B); logical
// chunk c of row r lives at physical slot c ^ (r & 7)  (XOR bank swizzle).
template<bool RELU, bool HAS_BIAS, int CAUSAL, int TMp, int TNp, bool MULTI, typename OT>
__global__ __launch_bounds__(256) void gemm_f16(
    const _Float16* __restrict__ A, const _Float16* __restrict__ BT,
    const float* __restrict__ bias0, const float* __restrict__ bias1,
    const float* __restrict__ bias2,
    OT* __restrict__ C0, OT* __restrict__ C1, OT* __restrict__ C2,
    int M, int Nout, int K, float scale,
    long long sA, long long sB, long long sC)
{
  int m0, n0;
  if (CAUSAL == 1) {
    int bx = blockIdx.x;                 // packed lower-tri: 2(i+1) j-tiles per i
    int i = (int)((sqrtf(4.f * bx + 1.f) - 1.f) * 0.5f);
    while ((i + 1) * (i + 2) <= bx) ++i;
    while (i * (i + 1) > bx) --i;
    int j = bx - i * (i + 1);
    m0 = i * TMp;
    n0 = j * TNp;
  } else {
    m0 = blockIdx.y * TMp;
    n0 = blockIdx.x * TNp;
  }
  A  += (long long)blockIdx.z * sA;
  BT += (long long)blockIdx.z * sB;
  const int kend = (CAUSAL == 2) ? ((m0 + TMp < K) ? m0 + TMp : K) : K;

  __shared__ _Float16 Ah[TMp * BK];
  __shared__ _Float16 Bh[TNp * BK];

  const int tid  = threadIdx.x;
  const int lane = tid & 63;
  const int wid  = tid >> 6;
  const int wm   = (wid >> 1) * (TMp / 2);
  const int wn   = (wid & 1) * (TNp / 2);
  const int l15  = lane & 15;
  const int quad = lane >> 4;
  constexpr int MT = TMp / 32;
  constexpr int NT = TNp / 32;

  f32x4 acc[MT][NT];
  #pragma unroll
  for (int i = 0; i < MT; ++i)
    #pragma unroll
    for (int j = 0; j < NT; ++j)
      acc[i][j] = (f32x4){0.f, 0.f, 0.f, 0.f};

  // staging: one gload_lds16 covers 8 rows x 64 halves (1 KB). lane ->
  // row = base + lane>>3, phys chunk = lane&7; source k-offset is the
  // swizzled logical chunk (lane&7)^(lane>>3).
  constexpr int AI = TMp / 32;           // instrs per wave for A
  constexpr int BI = TNp / 32;
  const int rl8  = lane >> 3;
  const int swk  = ((lane & 7) ^ rl8) * 8;     // halves
  const int arow = wid * (TMp / 4);
  const int brow = wid * (TNp / 4);

  for (int k0 = 0; k0 < kend; k0 += BK) {
    #pragma unroll
    for (int t = 0; t < AI; ++t)
      gload_lds16(A + (long long)(m0 + arow + t * 8 + rl8) * K + k0 + swk,
                  Ah + (arow + t * 8) * BK);
    #pragma unroll
    for (int t = 0; t < BI; ++t)
      gload_lds16(BT + (long long)(n0 + brow + t * 8 + rl8) * K + k0 + swk,
                  Bh + (brow + t * 8) * BK);
    __syncthreads();

    const _Float16* ab = Ah + (wm + l15) * BK;
    const _Float16* bb = Bh + (wn + l15) * BK;
    const int sw8 = l15 & 7;
    #pragma unroll
    for (int ko = 0; ko < 2; ++ko) {
      const int ch = ((ko * 4 + quad) ^ sw8) * 8;   // swizzled slot
      f16x8 af[MT], bf[NT];
      #pragma unroll
      for (int t = 0; t < MT; ++t) af[t] = *(const f16x8*)(ab + t * 16 * BK + ch);
      #pragma unroll
      for (int t = 0; t < NT; ++t) bf[t] = *(const f16x8*)(bb + t * 16 * BK + ch);
      #pragma unroll
      for (int mt = 0; mt < MT; ++mt)
        #pragma unroll
        for (int nt = 0; nt < NT; ++nt)
          acc[mt][nt] = __builtin_amdgcn_mfma_f32_16x16x32_f16(
              af[mt], bf[nt], acc[mt][nt], 0, 0, 0);
    }
    __syncthreads();
  }

  // epilogue; C/D layout: col = lane&15, row = quad*4 + reg (HW-verified)
  const int mat = MULTI ? (n0 / Nout) : 0;
  const float* bias = HAS_BIAS ? (mat == 0 ? bias0 : (mat == 1 ? bias1 : bias2)) : nullptr;
  OT* C = (mat == 0 ? C0 : (mat == 1 ? C1 : C2)) + (long long)blockIdx.z * sC;
  const int c0 = MULTI ? (n0 - mat * Nout) : n0;

  float bvals[NT];
  if (HAS_BIAS) {
    #pragma unroll
    for (int nt = 0; nt < NT; ++nt)
      bvals[nt] = bias[c0 + wn + nt * 16 + l15];
  }
  #pragma unroll
  for (int mt = 0; mt < MT; ++mt) {
    #pragma unroll
    for (int nt = 0; nt < NT; ++nt) {
      const int col = c0 + wn + nt * 16 + l15;
      #pragma unroll
      for (int r = 0; r < 4; ++r) {
        const int row = m0 + wm + mt * 16 + quad * 4 + r;
        float v = acc[mt][nt][r] * scale;
        if (HAS_BIAS) v += bvals[nt];
        if (RELU) v = fmaxf(v, 0.f);
        C[(long long)row * Nout + col] = (OT)v;
      }
    }
  }
}

// fp32 -> fp16 elementwise, 8 per thread
__global__ __launch_bounds__(256) void cvt_f32_f16(
    const float* __restrict__ in, _Float16* __restrict__ out)
{
  const long long i = ((long long)blockIdx.x * 256 + threadIdx.x) * 8;
  float4 a = *(const float4*)(in + i);
  float4 b = *(const float4*)(in + i + 4);
  f16x8 o = {(_Float16)a.x, (_Float16)a.y, (_Float16)a.z, (_Float16)a.w,
             (_Float16)b.x, (_Float16)b.y, (_Float16)b.z, (_Float16)b.w};
  *(f16x8*)(out + i) = o;
}

// All four W [K,N] fp32 -> concat WT [4N, K] fp16; z selects matrix.
__global__ __launch_bounds__(256) void cvtT_all(
    const float* __restrict__ W0, const float* __restrict__ W1,
    const float* __restrict__ W2, const float* __restrict__ W3,
    _Float16* __restrict__ WT, int K, int N)
{
  __shared__ _Float16 t[64][72];
  const int z = blockIdx.z;
  const float* W = (z == 0) ? W0 : (z == 1) ? W1 : (z == 2) ? W2 : W3;
  _Float16* dst = WT + (long long)z * K * N;
  const int k0 = blockIdx.x * 64, n0 = blockIdx.y * 64;
  const int tid = threadIdx.x;
  #pragma unroll
  for (int it = 0; it < 4; ++it) {
    int idx = tid + it * 256;
    int r = idx >> 4, c4 = (idx & 15) << 2;
    float4 w = *(const float4*)(W + (long long)(k0 + r) * N + n0 + c4);
    t[r][c4 + 0] = (_Float16)w.x; t[r][c4 + 1] = (_Float16)w.y;
    t[r][c4 + 2] = (_Float16)w.z; t[r][c4 + 3] = (_Float16)w.w;
  }
  __syncthreads();
  #pragma unroll
  for (int it = 0; it < 2; ++it) {
    int idx = tid + it * 256;
    int r = idx >> 3, c8 = (idx & 7) << 3;
    f16x8 o;
    #pragma unroll
    for (int j = 0; j < 8; ++j) o[j] = t[c8 + j][r];
    *(f16x8*)(dst + (long long)(n0 + r) * K + k0 + c8) = o;
  }
}

// in-place causal softmax, fp32 math, f16 IO; zeros for j > i
__global__ __launch_bounds__(256) void softmax_causal_h(
    _Float16* __restrict__ E, int S)
{
  const int i = blockIdx.x;
  _Float16* row = E + ((long long)blockIdx.y * S + i) * S;
  const int tid = threadIdx.x;
  const int n = i + 1;
  const int j0 = tid * 8;

  f16x8 hv = *(const f16x8*)(row + j0);
  float vals[8];
  float m = -3.0e38f;
  #pragma unroll
  for (int t = 0; t < 8; ++t) {
    float v = (j0 + t < n) ? (float)hv[t] : -3.0e38f;
    vals[t] = v;
    m = fmaxf(m, v);
  }
  #pragma unroll
  for (int o = 32; o > 0; o >>= 1) m = fmaxf(m, __shfl_down(m, o, 64));

  __shared__ float rmax[4];
  __shared__ float rsum[4];
  const int wave = tid >> 6;
  if ((tid & 63) == 0) rmax[wave] = m;
  __syncthreads();
  m = fmaxf(fmaxf(rmax[0], rmax[1]), fmaxf(rmax[2], rmax[3]));

  float s = 0.f;
  #pragma unroll
  for (int t = 0; t < 8; ++t) {
    float e = (j0 + t < n) ? expf(vals[t] - m) : 0.f;
    vals[t] = e;
    s += e;
  }
  #pragma unroll
  for (int o = 32; o > 0; o >>= 1) s += __shfl_down(s, o, 64);
  if ((tid & 63) == 0) rsum[wave] = s;
  __syncthreads();
  s = rsum[0] + rsum[1] + rsum[2] + rsum[3];

  const float inv = 1.0f / s;
  f16x8 ov;
  #pragma unroll
  for (int t = 0; t < 8; ++t) ov[t] = (_Float16)(vals[t] * inv);
  *(f16x8*)(row + j0) = ov;
}

extern "C" void kernel_launch(void* const* d_in, const int* in_sizes, int n_in,
                              void* d_out, int out_size, void* d_ws, size_t ws_size,
                              hipStream_t stream) {
  const float* x  = (const float*)d_in[0];
  const float* Wq = (const float*)d_in[1];
  const float* bq = (const float*)d_in[2];
  const float* Wk = (const float*)d_in[3];
  const float* bk = (const float*)d_in[4];
  const float* Wv = (const float*)d_in[5];
  const float* bv = (const float*)d_in[6];
  const float* Wo = (const float*)d_in[7];
  const float* bo = (const float*)d_in[8];
  float* out = (float*)d_out;

  const int Bn = 2, S = 2048, D = 1024;
  const int M = Bn * S;                       // 4096
  const size_t MD = (size_t)M * D;            // 4M elems
  const size_t DD = (size_t)D * D;            // 1M
  const size_t SS = (size_t)Bn * S * S;       // 8M

  _Float16* ws   = (_Float16*)d_ws;
  _Float16* xh   = ws;                 // MD
  _Float16* Wcat = xh + MD;            // 4*DD: Wq^T,Wk^T,Wv^T,Wo^T
  _Float16* Qh   = Wcat + 4 * DD;      // MD
  _Float16* Kh   = Qh + MD;            // MD
  _Float16* Vh   = Kh + MD;            // MD
  _Float16* VWT  = Vh + MD;            // MD   ((V@Wo)^T, [D,S] per batch)
  _Float16* E    = VWT + MD;           // SS

  dim3 blk(256);

  cvt_f32_f16<<<dim3((unsigned)(MD / 2048)), blk, 0, stream>>>(x, xh);
  cvtT_all<<<dim3(D / 64, D / 64, 4), blk, 0, stream>>>(Wq, Wk, Wv, Wo, Wcat, D, D);

  // fused QKV: relu(x@W{q,k,v} + b) -> f16, grid 768 = 3 blocks/CU
  gemm_f16<true, true, 0, 128, 128, true, _Float16>
      <<<dim3(3 * D / 128, M / 128), blk, 0, stream>>>(
      xh, Wcat, bq, bk, bv, Qh, Kh, Vh, M, D, D, 1.0f, 0, 0, 0);

  // E = QK^T/32, packed triangular grid (TM=128, TN=64): 272 tiles/batch
  gemm_f16<false, false, 1, 128, 64, false, _Float16>
      <<<dim3(272, 1, Bn), blk, 0, stream>>>(
      Qh, Kh, nullptr, nullptr, nullptr, E, nullptr, nullptr,
      S, S, D, 0.03125f, (long long)S * D, (long long)S * D, (long long)S * S);

  // VWT[d,j] = sum_e Wo[e,d] V[j,e]  (A = Wo^T shared, BT = V per batch)
  gemm_f16<false, false, 0, 128, 64, false, _Float16>
      <<<dim3(S / 64, D / 128, Bn), blk, 0, stream>>>(
      Wcat + 3 * DD, Vh, nullptr, nullptr, nullptr, VWT, nullptr, nullptr,
      D, S, D, 1.0f, 0, (long long)S * D, (long long)D * S);

  softmax_causal_h<<<dim3(S, Bn), blk, 0, stream>>>(E, S);

  // out = relu(P @ VW + bo) -> fp32 directly (causal k-cap, TM=64)
  gemm_f16<true, true, 2, 64, 128, false, float>
      <<<dim3(D / 128, S / 64, Bn), blk, 0, stream>>>(
      E, VWT, bo, nullptr, nullptr, out, nullptr, nullptr,
      S, D, S, 1.0f, (long long)S * S, (long long)D * S, (long long)S * D);
}

// Round 5
// 208.767 us; speedup vs baseline: 5.0178x; 1.0025x over previous
//
#include <hip/hip_runtime.h>
#include <math.h>

// fp16-MFMA fused MHA-like layer (fp32 accumulate), round 5:
//  - BK=32 (occupancy; m132 lesson) + XOR swizzle phys_chunk = c ^ ((row>>1)&3)
//    -> zero LDS bank conflicts AND 16KB LDS
//  - 5 dispatches: prep (cvt+cvtT), QKV, mid (QK^T || V@Wo), softmax, PV->out
//  - PV y-mapping reversed (heavy causal tiles first)

typedef _Float16 f16x8 __attribute__((ext_vector_type(8)));
typedef float f32x4 __attribute__((ext_vector_type(4)));

#define BK 32   // halves per LDS row (64 B)

__device__ __forceinline__ void gload_lds16(const void* g, void* l) {
  __builtin_amdgcn_global_load_lds(
      (const __attribute__((address_space(1))) void*)g,
      (__attribute__((address_space(3))) void*)l, 16, 0, 0);
}

// Accumulate C-tile (m0,n0) of A[*,sAr] @ BT[*,sBr]^T over k < kend.
// LDS layout: [row][chunk] chunks of 8 halves; logical chunk c of row r at
// physical slot c ^ ((r>>1)&3). Staging swizzles the global source side
// (global_load_lds LDS dest must stay lane-linear); ds_read mirrors it.
template<int TMp, int TNp>
__device__ __forceinline__ void gemm_acc(
    const _Float16* __restrict__ A, const _Float16* __restrict__ BT,
    _Float16* Ah, _Float16* Bh, int sAr, int sBr, int kend, int m0, int n0,
    f32x4 (&acc)[TMp / 32][TNp / 32])
{
  const int tid  = threadIdx.x;
  const int lane = tid & 63;
  const int wid  = tid >> 6;
  const int wm   = (wid >> 1) * (TMp / 2);
  const int wn   = (wid & 1) * (TNp / 2);
  const int l15  = lane & 15;
  const int quad = lane >> 4;
  constexpr int MT = TMp / 32;
  constexpr int NT = TNp / 32;
  constexpr int AI = TMp / 64;            // staging instrs per wave
  constexpr int BI = TNp / 64;
  const int r16 = lane >> 2;              // row within 16-row group
  const int swc = ((lane & 3) ^ ((lane >> 3) & 3)) * 8;  // swizzled src chunk
  const int arow = wid * (TMp / 4);
  const int brow = wid * (TNp / 4);

  for (int k0 = 0; k0 < kend; k0 += BK) {
    #pragma unroll
    for (int t = 0; t < AI; ++t)
      gload_lds16(A + (long long)(m0 + arow + t * 16 + r16) * sAr + k0 + swc,
                  Ah + (arow + t * 16) * BK);
    #pragma unroll
    for (int t = 0; t < BI; ++t)
      gload_lds16(BT + (long long)(n0 + brow + t * 16 + r16) * sBr + k0 + swc,
                  Bh + (brow + t * 16) * BK);
    __syncthreads();

    const int ch = (quad ^ ((l15 >> 1) & 3)) * 8;     // swizzled slot
    const _Float16* ab = Ah + (wm + l15) * BK + ch;
    const _Float16* bb = Bh + (wn + l15) * BK + ch;
    f16x8 af[MT], bf[NT];
    #pragma unroll
    for (int t = 0; t < MT; ++t) af[t] = *(const f16x8*)(ab + t * 16 * BK);
    #pragma unroll
    for (int t = 0; t < NT; ++t) bf[t] = *(const f16x8*)(bb + t * 16 * BK);
    #pragma unroll
    for (int mt = 0; mt < MT; ++mt)
      #pragma unroll
      for (int nt = 0; nt < NT; ++nt)
        acc[mt][nt] = __builtin_amdgcn_mfma_f32_16x16x32_f16(
            af[mt], bf[nt], acc[mt][nt], 0, 0, 0);
    __syncthreads();
  }
}

// Epilogue. C/D layout: col = lane&15, row = quad*4 + reg (HW-verified).
template<int TMp, int TNp, bool RELU, bool HAS_BIAS, typename OT>
__device__ __forceinline__ void gemm_store(
    f32x4 (&acc)[TMp / 32][TNp / 32], const float* __restrict__ bias,
    OT* __restrict__ C, int Nout, float scale, int m0, int n0)
{
  const int tid  = threadIdx.x;
  const int lane = tid & 63;
  const int wid  = tid >> 6;
  const int wm   = (wid >> 1) * (TMp / 2);
  const int wn   = (wid & 1) * (TNp / 2);
  const int l15  = lane & 15;
  const int quad = lane >> 4;
  constexpr int MT = TMp / 32;
  constexpr int NT = TNp / 32;

  float bvals[NT];
  if (HAS_BIAS) {
    #pragma unroll
    for (int nt = 0; nt < NT; ++nt)
      bvals[nt] = bias[n0 + wn + nt * 16 + l15];
  }
  #pragma unroll
  for (int mt = 0; mt < MT; ++mt) {
    #pragma unroll
    for (int nt = 0; nt < NT; ++nt) {
      const int col = n0 + wn + nt * 16 + l15;
      #pragma unroll
      for (int r = 0; r < 4; ++r) {
        const int row = m0 + wm + mt * 16 + quad * 4 + r;
        float v = acc[mt][nt][r] * scale;
        if (HAS_BIAS) v += bvals[nt];
        if (RELU) v = fmaxf(v, 0.f);
        C[(long long)row * Nout + col] = (OT)v;
      }
    }
  }
}

// fused QKV: relu(x @ W{q,k,v} + b) -> f16; Wcat = [Wq^T;Wk^T;Wv^T;Wo^T]
__global__ __launch_bounds__(256) void qkv_kernel(
    const _Float16* __restrict__ xh, const _Float16* __restrict__ Wcat,
    const float* __restrict__ bq, const float* __restrict__ bk,
    const float* __restrict__ bv,
    _Float16* __restrict__ Qh, _Float16* __restrict__ Kh,
    _Float16* __restrict__ Vh, int D)
{
  __shared__ _Float16 Ah[128 * BK];
  __shared__ _Float16 Bh[128 * BK];
  const int m0  = blockIdx.y * 128;
  const int n0g = blockIdx.x * 128;       // 0..3071
  f32x4 acc[4][4];
  #pragma unroll
  for (int i = 0; i < 4; ++i)
    #pragma unroll
    for (int j = 0; j < 4; ++j) acc[i][j] = (f32x4){0.f, 0.f, 0.f, 0.f};

  gemm_acc<128, 128>(xh, Wcat, Ah, Bh, D, D, D, m0, n0g, acc);

  const int mat = n0g >> 10;              // D = 1024
  const int c0  = n0g & 1023;
  _Float16* C = (mat == 0) ? Qh : (mat == 1) ? Kh : Vh;
  const float* bias = (mat == 0) ? bq : (mat == 1) ? bk : bv;
  gemm_store<128, 128, true, true, _Float16>(acc, bias, C, D, 1.0f, m0, c0);
}

// mid: blocks 0..543 -> E = QK^T/32 (packed triangular, TM=128,TN=64);
//      blocks 544..1055 -> VWT = (V@Wo)^T (A = Wo^T, BT = V).
__global__ __launch_bounds__(256) void mid_kernel(
    const _Float16* __restrict__ Qh, const _Float16* __restrict__ Kh,
    _Float16* __restrict__ E, const _Float16* __restrict__ WoT,
    const _Float16* __restrict__ Vh, _Float16* __restrict__ VWT,
    int S, int D)
{
  __shared__ _Float16 Ah[128 * BK];
  __shared__ _Float16 Bh[64 * BK];
  const _Float16 *A, *BT;
  _Float16* C;
  int m0, n0;
  float scale;
  const int id = blockIdx.x;
  if (id < 544) {                          // QK^T, 272 tiles per batch
    const int z = (id >= 272);
    const int t = id - z * 272;
    int i = (int)((sqrtf(4.f * t + 1.f) - 1.f) * 0.5f);
    while ((i + 1) * (i + 2) <= t) ++i;
    while (i * (i + 1) > t) --i;
    const int j = t - i * (i + 1);         // 0..2i+1
    m0 = i * 128;
    n0 = j * 64;
    A  = Qh + (long long)z * S * D;
    BT = Kh + (long long)z * S * D;
    C  = E + (long long)z * S * S;
    scale = 0.03125f;
  } else {                                 // V @ Wo, 256 tiles per batch
    const int t = id - 544;
    const int z = t >> 8;
    const int u = t & 255;
    m0 = (u >> 5) * 128;                   // D rows of Wo^T
    n0 = (u & 31) * 64;                    // S cols (V rows)
    A  = WoT;
    BT = Vh + (long long)z * S * D;
    C  = VWT + (long long)z * D * S;
    scale = 1.0f;
  }
  f32x4 acc[4][2];
  #pragma unroll
  for (int i = 0; i < 4; ++i)
    #pragma unroll
    for (int j = 0; j < 2; ++j) acc[i][j] = (f32x4){0.f, 0.f, 0.f, 0.f};

  gemm_acc<128, 64>(A, BT, Ah, Bh, D, D, D, m0, n0, acc);
  gemm_store<128, 64, false, false, _Float16>(acc, nullptr, C, S, scale, m0, n0);
}

// out = relu(P @ VW + bo) -> fp32; kend = m0+64 (causal cap); heavy tiles first
__global__ __launch_bounds__(256) void pv_kernel(
    const _Float16* __restrict__ E, const _Float16* __restrict__ VWT,
    const float* __restrict__ bo, float* __restrict__ out, int S, int D)
{
  __shared__ _Float16 Ah[64 * BK];
  __shared__ _Float16 Bh[128 * BK];
  const int z  = blockIdx.z;
  const int m0 = ((int)gridDim.y - 1 - (int)blockIdx.y) * 64;
  const int n0 = blockIdx.x * 128;
  const _Float16* A  = E + (long long)z * S * S;
  const _Float16* BT = VWT + (long long)z * D * S;
  float* C = out + (long long)z * S * D;
  const int kend = m0 + 64;

  f32x4 acc[2][4];
  #pragma unroll
  for (int i = 0; i < 2; ++i)
    #pragma unroll
    for (int j = 0; j < 4; ++j) acc[i][j] = (f32x4){0.f, 0.f, 0.f, 0.f};

  gemm_acc<64, 128>(A, BT, Ah, Bh, S, S, kend, m0, n0, acc);
  gemm_store<64, 128, true, true, float>(acc, bo, C, D, 1.0f, m0, n0);
}

// prep: blocks 0..2047 = x fp32->f16 (8 elems/thread);
//       blocks 2048..3071 = W transpose+convert into Wcat (64x64 tiles, z=mat)
__global__ __launch_bounds__(256) void prep_kernel(
    const float* __restrict__ x, _Float16* __restrict__ xh,
    const float* __restrict__ W0, const float* __restrict__ W1,
    const float* __restrict__ W2, const float* __restrict__ W3,
    _Float16* __restrict__ Wcat, int D)
{
  const int id = blockIdx.x;
  const int tid = threadIdx.x;
  if (id < 2048) {
    const long long i = ((long long)id * 256 + tid) * 8;
    float4 a = *(const float4*)(x + i);
    float4 b = *(const float4*)(x + i + 4);
    f16x8 o = {(_Float16)a.x, (_Float16)a.y, (_Float16)a.z, (_Float16)a.w,
               (_Float16)b.x, (_Float16)b.y, (_Float16)b.z, (_Float16)b.w};
    *(f16x8*)(xh + i) = o;
    return;
  }
  __shared__ _Float16 t[64][72];
  const int u = id - 2048;
  const int z = u >> 8;
  const int v = u & 255;
  const float* W = (z == 0) ? W0 : (z == 1) ? W1 : (z == 2) ? W2 : W3;
  _Float16* dst = Wcat + (long long)z * D * D;
  const int k0 = (v >> 4) * 64, n0 = (v & 15) * 64;
  #pragma unroll
  for (int it = 0; it < 4; ++it) {
    int idx = tid + it * 256;
    int r = idx >> 4, c4 = (idx & 15) << 2;
    float4 w = *(const float4*)(W + (long long)(k0 + r) * D + n0 + c4);
    t[r][c4 + 0] = (_Float16)w.x; t[r][c4 + 1] = (_Float16)w.y;
    t[r][c4 + 2] = (_Float16)w.z; t[r][c4 + 3] = (_Float16)w.w;
  }
  __syncthreads();
  #pragma unroll
  for (int it = 0; it < 2; ++it) {
    int idx = tid + it * 256;
    int r = idx >> 3, c8 = (idx & 7) << 3;
    f16x8 o;
    #pragma unroll
    for (int j = 0; j < 8; ++j) o[j] = t[c8 + j][r];
    *(f16x8*)(dst + (long long)(n0 + r) * D + k0 + c8) = o;
  }
}

// in-place causal softmax, fp32 math, f16 IO; zeros for j > i
__global__ __launch_bounds__(256) void softmax_causal_h(
    _Float16* __restrict__ E, int S)
{
  const int i = blockIdx.x;
  _Float16* row = E + ((long long)blockIdx.y * S + i) * S;
  const int tid = threadIdx.x;
  const int n = i + 1;
  const int j0 = tid * 8;

  f16x8 hv = *(const f16x8*)(row + j0);
  float vals[8];
  float m = -3.0e38f;
  #pragma unroll
  for (int t = 0; t < 8; ++t) {
    float v = (j0 + t < n) ? (float)hv[t] : -3.0e38f;
    vals[t] = v;
    m = fmaxf(m, v);
  }
  #pragma unroll
  for (int o = 32; o > 0; o >>= 1) m = fmaxf(m, __shfl_down(m, o, 64));

  __shared__ float rmax[4];
  __shared__ float rsum[4];
  const int wave = tid >> 6;
  if ((tid & 63) == 0) rmax[wave] = m;
  __syncthreads();
  m = fmaxf(fmaxf(rmax[0], rmax[1]), fmaxf(rmax[2], rmax[3]));

  float s = 0.f;
  #pragma unroll
  for (int t = 0; t < 8; ++t) {
    float e = (j0 + t < n) ? expf(vals[t] - m) : 0.f;
    vals[t] = e;
    s += e;
  }
  #pragma unroll
  for (int o = 32; o > 0; o >>= 1) s += __shfl_down(s, o, 64);
  if ((tid & 63) == 0) rsum[wave] = s;
  __syncthreads();
  s = rsum[0] + rsum[1] + rsum[2] + rsum[3];

  const float inv = 1.0f / s;
  f16x8 ov;
  #pragma unroll
  for (int t = 0; t < 8; ++t) ov[t] = (_Float16)(vals[t] * inv);
  *(f16x8*)(row + j0) = ov;
}

extern "C" void kernel_launch(void* const* d_in, const int* in_sizes, int n_in,
                              void* d_out, int out_size, void* d_ws, size_t ws_size,
                              hipStream_t stream) {
  const float* x  = (const float*)d_in[0];
  const float* Wq = (const float*)d_in[1];
  const float* bq = (const float*)d_in[2];
  const float* Wk = (const float*)d_in[3];
  const float* bk = (const float*)d_in[4];
  const float* Wv = (const float*)d_in[5];
  const float* bv = (const float*)d_in[6];
  const float* Wo = (const float*)d_in[7];
  const float* bo = (const float*)d_in[8];
  float* out = (float*)d_out;

  const int Bn = 2, S = 2048, D = 1024;
  const int M = Bn * S;                       // 4096
  const size_t MD = (size_t)M * D;            // 4M elems
  const size_t DD = (size_t)D * D;            // 1M
  const size_t SS = (size_t)Bn * S * S;       // 8M

  _Float16* ws   = (_Float16*)d_ws;
  _Float16* xh   = ws;                 // MD
  _Float16* Wcat = xh + MD;            // 4*DD
  _Float16* Qh   = Wcat + 4 * DD;      // MD
  _Float16* Kh   = Qh + MD;            // MD
  _Float16* Vh   = Kh + MD;            // MD
  _Float16* VWT  = Vh + MD;            // MD  ((V@Wo)^T, [D,S] per batch)
  _Float16* E    = VWT + MD;           // SS

  dim3 blk(256);

  prep_kernel<<<dim3(3072), blk, 0, stream>>>(x, xh, Wq, Wk, Wv, Wo, Wcat, D);

  qkv_kernel<<<dim3(3 * D / 128, M / 128), blk, 0, stream>>>(
      xh, Wcat, bq, bk, bv, Qh, Kh, Vh, D);

  mid_kernel<<<dim3(1056), blk, 0, stream>>>(
      Qh, Kh, E, Wcat + 3 * DD, Vh, VWT, S, D);

  softmax_causal_h<<<dim3(S, Bn), blk, 0, stream>>>(E, S);

  pv_kernel<<<dim3(D / 128, S / 64, Bn), blk, 0, stream>>>(
      E, VWT, bo, out, S, D);
}